// Round 8
// baseline (292.971 us; speedup 1.0000x reference)
//
#include <hip/hip_runtime.h>
#include <hip/hip_bf16.h>

#define NUM_NODES 50000
#define DIM 64
#define NUM_EDGES 800000
#define NUM_GRAPHS 3
#define TOT_NODES (NUM_NODES * NUM_GRAPHS)      // 150000
#define TOT_EDGES (NUM_EDGES * NUM_GRAPHS)      // 2400000
#define EPS 1e-12f

#define NB 196                                   // buckets per graph: dst>>8
#define TB (NB * NUM_GRAPHS)                     // 588 total buckets
#define P3_CHUNK 8192
#define P3_BLOCKS ((NUM_EDGES + P3_CHUNK - 1) / P3_CHUNK)   // 98
#define PCAP 5120                                // padded bucket capacity (mean 4096, +16 sigma)

typedef unsigned short ushort_t;
typedef unsigned int uint_t;
typedef unsigned short ushort8v __attribute__((ext_vector_type(8)));   // 16 B
typedef unsigned int uint4v __attribute__((ext_vector_type(4)));       // 16 B

__device__ __forceinline__ float bf2f(ushort_t u) {
    return __uint_as_float(((uint_t)u) << 16);
}
__device__ __forceinline__ ushort_t f2bf(float f) {
    uint_t x = __float_as_uint(f);
    uint_t r = (x + 0x7FFFu + ((x >> 16) & 1u)) >> 16;   // RNE
    return (ushort_t)r;
}

// unpack 8 bf16 (as uint4) and accumulate a[j] += d * v[j]; 1 VALU per element for unpack
__device__ __forceinline__ void unpack_fma(uint4v w, float d, float* a) {
    a[0] += d * __uint_as_float(w[0] << 16);
    a[1] += d * __uint_as_float(w[0] & 0xFFFF0000u);
    a[2] += d * __uint_as_float(w[1] << 16);
    a[3] += d * __uint_as_float(w[1] & 0xFFFF0000u);
    a[4] += d * __uint_as_float(w[2] << 16);
    a[5] += d * __uint_as_float(w[2] & 0xFFFF0000u);
    a[6] += d * __uint_as_float(w[3] << 16);
    a[7] += d * __uint_as_float(w[3] & 0xFFFF0000u);
}
__device__ __forceinline__ void unpack_add(uint4v w, float* a) {
    a[0] += __uint_as_float(w[0] << 16);
    a[1] += __uint_as_float(w[0] & 0xFFFF0000u);
    a[2] += __uint_as_float(w[1] << 16);
    a[3] += __uint_as_float(w[1] & 0xFFFF0000u);
    a[4] += __uint_as_float(w[2] << 16);
    a[5] += __uint_as_float(w[2] & 0xFFFF0000u);
    a[6] += __uint_as_float(w[3] << 16);
    a[7] += __uint_as_float(w[3] & 0xFFFF0000u);
}

// ---------------- L2 normalize input -> bf16 shared table ----------------
__global__ void l2norm_kernel(const float* __restrict__ in, ushort_t* __restrict__ out) {
    int row = blockIdx.x * (blockDim.x >> 6) + (threadIdx.x >> 6);
    int lane = threadIdx.x & 63;
    if (row >= NUM_NODES) return;
    float v = in[(long)row * DIM + lane];
    float s = v * v;
    #pragma unroll
    for (int off = 32; off > 0; off >>= 1)
        s += __shfl_xor(s, off, 64);
    float inv = 1.0f / fmaxf(sqrtf(s), EPS);
    out[(long)row * DIM + lane] = f2bf(v * inv);
}

// ---------------- partition edges into padded buckets (LDS-staged) ----------------
__global__ void partition_kernel(const int* __restrict__ e0, const int* __restrict__ e1,
                                 const int* __restrict__ e2,
                                 int* __restrict__ gcnt, uint_t* __restrict__ part) {
    __shared__ uint_t recs[P3_CHUNK];        // 32 KB
    __shared__ int h[NB], lstart[NB], gbase[NB], lcur[NB];
    __shared__ int sc[256];

    int g = blockIdx.y;
    const int* ei = (g == 0) ? e0 : (g == 1) ? e1 : e2;
    const int* srcp = ei;
    const int* dstp = ei + NUM_EDGES;
    int base = blockIdx.x * P3_CHUNK;
    int n = min(P3_CHUNK, NUM_EDGES - base);
    int t = threadIdx.x;

    for (int i = t; i < NB; i += 256) h[i] = 0;
    __syncthreads();
    for (int i = t; i < n; i += 256)
        atomicAdd(&h[dstp[base + i] >> 8], 1);
    __syncthreads();

    // block scan over NB (<=256) with 256 threads
    {
        int v = (t < NB) ? h[t] : 0;
        sc[t] = v;
        __syncthreads();
        #pragma unroll
        for (int off = 1; off < 256; off <<= 1) {
            int add = (t >= off) ? sc[t - off] : 0;
            __syncthreads();
            sc[t] += add;
            __syncthreads();
        }
        if (t < NB) {
            int ex = sc[t] - v;
            lstart[t] = ex;
            lcur[t] = ex;
            gbase[t] = (v > 0) ? atomicAdd(&gcnt[g * NB + t], v) : 0;
        }
    }
    __syncthreads();

    // place records into LDS, bucket-grouped
    for (int i = t; i < n; i += 256) {
        int s = srcp[base + i];
        int d = dstp[base + i];
        int pos = atomicAdd(&lcur[d >> 8], 1);
        recs[pos] = ((uint_t)d << 16) | (uint_t)s;
    }
    __syncthreads();

    // stream out: consecutive LDS slots -> consecutive global slots per bucket segment
    for (int i = t; i < n; i += 256) {
        uint_t r = recs[i];
        int b = r >> 24;                      // dst>>8 (dst < 2^16)
        int off = gbase[b] + (i - lstart[b]);
        if (off < PCAP)                       // capacity clamp (p ~ 0)
            part[(long)(g * NB + b) * PCAP + off] = r;
    }
}

// ---------------- per-bucket fine sort -> esort + row_start/row_end + dinv ----------------
__global__ void bucket_sort_kernel(const uint_t* __restrict__ part, const int* __restrict__ gcnt,
                                   ushort_t* __restrict__ esort, int* __restrict__ row_start,
                                   int* __restrict__ row_end, float* __restrict__ dinv) {
    __shared__ uint_t recs[PCAP];            // 20.5 KB
    __shared__ int lcur[256];
    __shared__ int sc[256];

    int b = blockIdx.x;                       // 0..TB-1
    int g = b / NB;
    int bhi = b % NB;
    long s0 = (long)b * PCAP;
    int n = min(gcnt[b], PCAP);
    int t = threadIdx.x;

    sc[t] = 0;   // histogram over dst-low
    __syncthreads();
    for (int i = t; i < n; i += 256) {
        uint_t r = part[s0 + i];
        recs[i] = r;
        atomicAdd(&sc[(r >> 16) & 255], 1);
    }
    __syncthreads();
    int v = sc[t];
    __syncthreads();
    sc[t] = v;
    __syncthreads();
    #pragma unroll
    for (int off = 1; off < 256; off <<= 1) {
        int add = (t >= off) ? sc[t - off] : 0;
        __syncthreads();
        sc[t] += add;
        __syncthreads();
    }
    int ex = sc[t] - v;
    lcur[t] = ex;

    int node = (bhi << 8) + t;
    if (node < NUM_NODES) {
        int k = g * NUM_NODES + node;
        row_start[k] = (int)s0 + ex;
        row_end[k]   = (int)s0 + ex + v;
        dinv[k] = (v > 0) ? rsqrtf((float)v) : 0.0f;
    }
    __syncthreads();

    for (int i = t; i < n; i += 256) {
        uint_t r = recs[i];
        int dl = (r >> 16) & 255;
        int pos = atomicAdd(&lcur[dl], 1);
        esort[s0 + pos] = (ushort_t)(r & 0xFFFFu);
    }
}

// ---------------- layer 1, 2D grid (row, g): b[t] = dinv_t^2 * sum dinv_s * xn[s] ----------------
__global__ void conv1_all_kernel(const ushort_t* __restrict__ xn,
                                 const ushort_t* __restrict__ esort,
                                 const int* __restrict__ row_start,
                                 const int* __restrict__ row_end,
                                 const float* __restrict__ dinv,
                                 ushort_t* __restrict__ bufA) {
    int row = blockIdx.x * (blockDim.x >> 6) + (threadIdx.x >> 6);
    int g = blockIdx.y;
    int lane = threadIdx.x & 63;
    int sub = lane >> 3;          // 0..7: which edge of the group
    int li  = lane & 7;           // 0..7: dims [li*8, li*8+8)
    if (row >= NUM_NODES) return;

    int k = g * NUM_NODES + row;
    int start = __builtin_amdgcn_readfirstlane(row_start[k]);
    int end   = __builtin_amdgcn_readfirstlane(row_end[k]);
    const float* dv = dinv + g * NUM_NODES;

    float a[8];
    #pragma unroll
    for (int j = 0; j < 8; ++j) a[j] = 0.0f;

    int i = start;
    for (; i + 16 <= end; i += 16) {
        int sA = esort[i + sub];
        int sB = esort[i + 8 + sub];
        float dA = dv[sA];
        float dB = dv[sB];
        uint4v rA = *(const uint4v*)(xn + (long)sA * DIM + li * 8);
        uint4v rB = *(const uint4v*)(xn + (long)sB * DIM + li * 8);
        unpack_fma(rA, dA, a);
        unpack_fma(rB, dB, a);
    }
    for (; i < end; i += 8) {
        int e = i + sub;
        if (e < end) {
            int s = esort[e];
            float d = dv[s];
            uint4v r = *(const uint4v*)(xn + (long)s * DIM + li * 8);
            unpack_fma(r, d, a);
        }
    }
    // combine the 8 sub-groups (dims aligned across subs)
    #pragma unroll
    for (int off = 8; off < 64; off <<= 1) {
        #pragma unroll
        for (int j = 0; j < 8; ++j)
            a[j] += __shfl_xor(a[j], off, 64);
    }
    float dt = dinv[k];
    float scl = dt * dt;
    if (sub == 0) {
        ushort8v o;
        #pragma unroll
        for (int j = 0; j < 8; ++j) o[j] = f2bf(a[j] * scl);
        *(ushort8v*)(bufA + (long)k * DIM + li * 8) = o;
    }
}

// ---------------- layer 2, per (row, g) with XCD graph affinity -> ybuf ----------------
// y_g[row] = w_g * a / ||a||  (dinv_t row-scale cancels under the norm)
__global__ void conv2_kernel(const ushort_t* __restrict__ bufA,
                             const ushort_t* __restrict__ esort,
                             const int* __restrict__ row_start,
                             const int* __restrict__ row_end,
                             const float* __restrict__ alpha,
                             ushort_t* __restrict__ ybuf) {
    // pseudo-XCD affinity: graphs pinned to XCD groups so each XCD's L2
    // only sees one 6.4 MB bufA table (mapping heuristic; correctness-free)
    const int gmap[8]   = {0, 1, 2, 0, 1, 2, 0, 1};
    const int idxmap[8] = {0, 0, 0, 1, 1, 1, 2, 2};
    const int cntmap[8] = {3, 3, 2, 3, 3, 2, 3, 3};

    int x = blockIdx.x & 7;
    int j = blockIdx.x >> 3;
    int g = gmap[x];
    int idx = idxmap[x];
    int cnt = cntmap[x];
    int chunk = (NUM_NODES + cnt - 1) / cnt;

    int row_local = j * 4 + (threadIdx.x >> 6);
    if (row_local >= chunk) return;
    int row = idx * chunk + row_local;
    if (row >= NUM_NODES) return;

    int lane = threadIdx.x & 63;
    int sub = lane >> 3;
    int li  = lane & 7;

    // softmax(alpha) -> clip -> renormalize, pick w[g]
    float al0 = alpha[0], al1 = alpha[1], al2 = alpha[2];
    float m = fmaxf(al0, fmaxf(al1, al2));
    float e0 = expf(al0 - m), e1 = expf(al1 - m), e2 = expf(al2 - m);
    float es = e0 + e1 + e2;
    float w0 = fmaxf(e0 / es, 1e-4f);
    float w1 = fmaxf(e1 / es, 1e-4f);
    float w2 = fmaxf(e2 / es, 1e-4f);
    float ws = w0 + w1 + w2;
    float w = ((g == 0) ? w0 : (g == 1) ? w1 : w2) / ws;

    int k = g * NUM_NODES + row;
    int start = __builtin_amdgcn_readfirstlane(row_start[k]);
    int end   = __builtin_amdgcn_readfirstlane(row_end[k]);
    const ushort_t* tbl = bufA + (long)g * NUM_NODES * DIM;

    float a[8];
    #pragma unroll
    for (int jj = 0; jj < 8; ++jj) a[jj] = 0.0f;

    int i = start;
    for (; i + 16 <= end; i += 16) {
        int sA = esort[i + sub];
        int sB = esort[i + 8 + sub];
        uint4v rA = *(const uint4v*)(tbl + (long)sA * DIM + li * 8);
        uint4v rB = *(const uint4v*)(tbl + (long)sB * DIM + li * 8);
        unpack_add(rA, a);
        unpack_add(rB, a);
    }
    for (; i < end; i += 8) {
        int e = i + sub;
        if (e < end) {
            int s = esort[e];
            uint4v r = *(const uint4v*)(tbl + (long)s * DIM + li * 8);
            unpack_add(r, a);
        }
    }
    #pragma unroll
    for (int off = 8; off < 64; off <<= 1) {
        #pragma unroll
        for (int jj = 0; jj < 8; ++jj)
            a[jj] += __shfl_xor(a[jj], off, 64);
    }
    // row L2 norm: each 8-lane group holds the full row (8 dims/lane)
    float s = 0.0f;
    #pragma unroll
    for (int jj = 0; jj < 8; ++jj) s += a[jj] * a[jj];
    #pragma unroll
    for (int off = 1; off < 8; off <<= 1)
        s += __shfl_xor(s, off, 64);
    float scl = w / fmaxf(sqrtf(s), EPS);

    if (sub == 0) {
        ushort8v o;
        #pragma unroll
        for (int jj = 0; jj < 8; ++jj) o[jj] = f2bf(a[jj] * scl);
        *(ushort8v*)(ybuf + (long)k * DIM + li * 8) = o;
    }
}

// ---------------- blend: out = y0 + y1 + y2 (streamed) ----------------
__global__ void blend_kernel(const ushort_t* __restrict__ ybuf, float* __restrict__ out) {
    int i = blockIdx.x * blockDim.x + threadIdx.x;   // 8-dim chunk id
    if (i >= NUM_NODES * DIM / 8) return;
    uint4v w0 = *(const uint4v*)(ybuf + (long)i * 8);
    uint4v w1 = *(const uint4v*)(ybuf + (long)NUM_NODES * DIM + (long)i * 8);
    uint4v w2 = *(const uint4v*)(ybuf + 2L * NUM_NODES * DIM + (long)i * 8);
    float r[8];
    #pragma unroll
    for (int jj = 0; jj < 8; ++jj) r[jj] = 0.0f;
    unpack_add(w0, r);
    unpack_add(w1, r);
    unpack_add(w2, r);
    float* p = out + (long)i * 8;
    *(float4*)p = make_float4(r[0], r[1], r[2], r[3]);
    *(float4*)(p + 4) = make_float4(r[4], r[5], r[6], r[7]);
}

extern "C" void kernel_launch(void* const* d_in, const int* in_sizes, int n_in,
                              void* d_out, int out_size, void* d_ws, size_t ws_size,
                              hipStream_t stream) {
    const float* x     = (const float*)d_in[0];
    const float* alpha = (const float*)d_in[1];
    const int* e0 = (const int*)d_in[2];
    const int* e1 = (const int*)d_in[3];
    const int* e2 = (const int*)d_in[4];
    float* out = (float*)d_out;

    // workspace layout (~65 MB)
    ushort_t* xn   = (ushort_t*)d_ws;                          // 3,200,000 bf16  (6.4 MB)
    ushort_t* bufA = xn + (long)NUM_NODES * DIM;               // 9,600,000 bf16  (19.2 MB)
    ushort_t* ybuf = bufA + (long)TOT_NODES * DIM;             // 9,600,000 bf16  (19.2 MB)
    float* dinv    = (float*)(ybuf + (long)TOT_NODES * DIM);   // 150,000 f32
    int* row_start = (int*)(dinv + TOT_NODES);                 // 150,016
    int* row_end   = row_start + 150016;                       // 150,016
    int* gcnt      = row_end + 150016;                         // 640
    uint_t* part   = (uint_t*)(gcnt + 640);                    // 588*5120 u32    (12.04 MB)
    ushort_t* esort = (ushort_t*)(part + (long)TB * PCAP);     // 588*5120 u16    (6.02 MB)

    const int wave_grid = (NUM_NODES * 64 + 255) / 256;        // 1 wave/row, 4 waves/block

    // normalize input once (f32 -> bf16 shared table)
    l2norm_kernel<<<wave_grid, 256, 0, stream>>>(x, xn);

    // ---- build padded-bucket CSR ----
    hipMemsetAsync(gcnt, 0, TB * sizeof(int), stream);
    {
        dim3 grd(P3_BLOCKS, NUM_GRAPHS);
        partition_kernel<<<grd, 256, 0, stream>>>(e0, e1, e2, gcnt, part);
    }
    bucket_sort_kernel<<<TB, 256, 0, stream>>>(part, gcnt, esort, row_start, row_end, dinv);

    // ---- layer 1 (2D grid: row x graph) ----
    {
        dim3 grd(wave_grid, NUM_GRAPHS);
        conv1_all_kernel<<<grd, 256, 0, stream>>>(xn, esort, row_start, row_end, dinv, bufA);
    }
    // ---- layer 2 per (row, graph) with XCD graph affinity ----
    {
        int blocks = 8 * ((25000 + 3) / 4);                    // 8 * 6250
        conv2_kernel<<<blocks, 256, 0, stream>>>(bufA, esort, row_start, row_end, alpha, ybuf);
    }
    // ---- blend ----
    {
        int n8 = NUM_NODES * DIM / 8;
        blend_kernel<<<(n8 + 255) / 256, 256, 0, stream>>>(ybuf, out);
    }
}